// Round 10
// baseline (339.782 us; speedup 1.0000x reference)
//
#include <hip/hip_runtime.h>
#include <stdint.h>
#include <limits.h>

// Problem constants (reference: B=4, N=8192, C=64, OUT=64, KNN=36)
#define BB 4
#define NN 8192
#define CC 64
#define OUTD 64
#define KK 36
#define NPTS (BB * NN)          // 32768
#define NBIN 129                // bins 0..128 (0 and 128 are clamp catch-alls)
// t = signed(float_bits(d2)) >> 20 (arith); bin = med3_i32(t,960,1088) - 960.
// Negative d2 (fp rounding) -> t very negative -> bin 0. One integer t per bin.

typedef float v2f __attribute__((ext_vector_type(2)));

static __device__ __forceinline__ int laneid() { return threadIdx.x & 63; }
static __device__ __forceinline__ int waveid_uniform() {
    return __builtin_amdgcn_readfirstlane((int)(threadIdx.x >> 6));
}

// ---------------------------------------------------------------------------
// Kernel 1: v_feat = relu([feature, xyz] @ W_v + b_v)  and pack xyzw=(x,y,z,|p|^2)
// One wave handles 8 points (shares each Wv row load across 8 accumulators).
// Block = 256 = 4 waves = 32 points. grid = NPTS/32 = 1024 blocks.
// ---------------------------------------------------------------------------
__global__ __launch_bounds__(256) void k_vfeat(
    const float* __restrict__ feat, const float* __restrict__ xyz,
    const float* __restrict__ Wv, const float* __restrict__ bv,
    float* __restrict__ vfeat, float4* __restrict__ xyzw)
{
    __shared__ float fb[4][8][64];
    __shared__ float xb[4][8][3];
    const int lane = laneid();
    const int wv = waveid_uniform();
    const int pbase = blockIdx.x * 32 + wv * 8;

    #pragma unroll
    for (int pp = 0; pp < 8; ++pp)
        fb[wv][pp][lane] = feat[(pbase + pp) * CC + lane];
    if (lane < 24)
        xb[wv][lane / 3][lane % 3] = xyz[pbase * 3 + lane];
    // same-wave LDS write->read: in-order per wave, compiler inserts lgkmcnt

    const float b0 = bv[lane];
    float acc[8];
    #pragma unroll
    for (int pp = 0; pp < 8; ++pp) acc[pp] = b0;

    #pragma unroll 4
    for (int c = 0; c < CC; ++c) {
        float w = Wv[c * OUTD + lane];
        #pragma unroll
        for (int pp = 0; pp < 8; ++pp)
            acc[pp] = fmaf(fb[wv][pp][c], w, acc[pp]);
    }
    const float wx = Wv[64 * OUTD + lane];
    const float wy = Wv[65 * OUTD + lane];
    const float wz = Wv[66 * OUTD + lane];
    #pragma unroll
    for (int pp = 0; pp < 8; ++pp) {
        float a = acc[pp];
        a = fmaf(xb[wv][pp][0], wx, a);
        a = fmaf(xb[wv][pp][1], wy, a);
        a = fmaf(xb[wv][pp][2], wz, a);
        vfeat[(pbase + pp) * OUTD + lane] = fmaxf(a, 0.0f);
    }
    if (lane < 8) {
        float x = xb[wv][lane][0], y = xb[wv][lane][1], z = xb[wv][lane][2];
        float sq = (x * x + y * y) + z * z;
        xyzw[pbase + lane] = make_float4(x, y, z, sq);
    }
}

// ---------------------------------------------------------------------------
// Kernel 2: 36-NN via per-query float-bit histogram selection.
// R3/R7 partitioning (512 blocks x 1024 thr, 64 queries/block = lane-per-query,
// 2 blocks/CU = 32 waves/CU), AoS float4 candidates via wave-uniform s_load.
// WINDOWED: 16 candidates per window -- all 8 loads issued, ONE lgkmcnt drain,
// 16 bin computes (v_pk_fma_f32 pairs), then 16 ds_adds. The previous window's
// atomics retire under this window's compute, instead of a drain per pair
// (s_load and ds_add share lgkmcnt; SMEM completes out-of-order -> consuming
// a load forces lgkmcnt(0) which drains ALL pending atomics).
// Histogram hist[bin][lane]: bank = lane%32, conflict-free 32-bit counts.
// Tie-break matches lax.top_k: (distance-bits, then smaller index).
// ---------------------------------------------------------------------------
__global__ __launch_bounds__(1024) void k_knn(
    const float4* __restrict__ xyzw, int* __restrict__ idx_ws)
{
    __shared__ __align__(16) uint32_t hist[NBIN * 64];  // 33 KB; reused as buf in pass 2
    __shared__ int binB[64];
    __shared__ int cumLoA[64];
    __shared__ uint32_t bufCnt[64];
    __shared__ uint32_t dirCnt[64];

    const int lane = laneid();
    const int wv = waveid_uniform();               // 0..15
    const int batch = blockIdx.x >> 7;             // 128 blocks per batch
    const int qbase = (blockIdx.x & 127) << 6;
    const int q = qbase + lane;                    // local query id 0..8191
    const float4* __restrict__ xw = xyzw + batch * NN;

    const float4 Q = xw[q];
    const v2f qx = { Q.x, Q.x };
    const v2f qy = { Q.y, Q.y };
    const v2f qz = { Q.z, Q.z };
    const v2f qw = { Q.w, Q.w };
    const v2f m2 = { -2.0f, -2.0f };

    const int j0 = wv * 512;
    const int laneAdj = lane - 960 * 64;           // fold bin rebase into addressing

    for (int i = threadIdx.x; i < NBIN * 64; i += 1024) hist[i] = 0u;
    if (threadIdx.x < 64) { bufCnt[threadIdx.x] = 0u; dirCnt[threadIdx.x] = 0u; }
    __syncthreads();

    // ---- pass 1: histogram (window = 16 candidates: load / compute / atomic) ----
    for (int j = j0; j < j0 + 512; j += 16) {
        float4 c[16];
        #pragma unroll
        for (int u = 0; u < 16; ++u) c[u] = xw[j + u];   // wave-uniform s_loads
        int m3[8 * 2];
        #pragma unroll
        for (int u = 0; u < 8; ++u) {
            v2f cx = { c[2*u].x, c[2*u+1].x }, cy = { c[2*u].y, c[2*u+1].y };
            v2f cz = { c[2*u].z, c[2*u+1].z }, cw = { c[2*u].w, c[2*u+1].w };
            v2f dot = __builtin_elementwise_fma(qx, cx,
                      __builtin_elementwise_fma(qy, cy, qz * cz));
            v2f d2  = __builtin_elementwise_fma(m2, dot, qw + cw);
            int t0 = ((int)__float_as_uint(d2.x)) >> 20;   // arith: neg d -> very neg
            int t1 = ((int)__float_as_uint(d2.y)) >> 20;
            m3[2*u]   = min(max(t0, 960), 1088);           // v_med3_i32
            m3[2*u+1] = min(max(t1, 960), 1088);
        }
        #pragma unroll
        for (int u = 0; u < 16; ++u)
            atomicAdd(&hist[m3[u] * 64 + laneAdj], 1u);    // == hist[bin*64+lane]
    }
    __syncthreads();

    // ---- find crossing bin (threads 0..63, one query each) ----
    if (threadIdx.x < 64) {
        int cum = 0, Bq = 128, cl = 0;
        for (int b2 = 0; b2 < NBIN; ++b2) {
            int c = (int)hist[b2 * 64 + threadIdx.x];
            if (cum + c >= KK) { Bq = b2; cl = cum; break; }
            cum += c;
        }
        binB[threadIdx.x] = Bq;
        cumLoA[threadIdx.x] = cl;
    }
    __syncthreads();

    // ---- per-lane integer thresholds for pass 2 ----
    // direct (bin < Bq)    <=>  t <  TL
    // boundary (bin == Bq) <=>  !direct && t <= TH
    const int Bq = binB[lane];
    const int TL = (Bq > 0)    ? (960 + Bq) : INT_MIN;
    const int TH = (Bq == 128) ? INT_MAX    : (960 + Bq);
    const int grow = batch * NN + q;

    // buf[pos][lane] (transposed): 64 pos x 64 lanes x 8B = 32 KB (inside hist)
    unsigned long long* buf = (unsigned long long*)hist;

    // ---- pass 2: windowed loads; rare exec-masked emits ----
    for (int j = j0; j < j0 + 512; j += 16) {
        float4 c[16];
        #pragma unroll
        for (int u = 0; u < 16; ++u) c[u] = xw[j + u];
        int tt[16]; float dd[16];
        #pragma unroll
        for (int u = 0; u < 8; ++u) {
            v2f cx = { c[2*u].x, c[2*u+1].x }, cy = { c[2*u].y, c[2*u+1].y };
            v2f cz = { c[2*u].z, c[2*u+1].z }, cw = { c[2*u].w, c[2*u+1].w };
            v2f dot = __builtin_elementwise_fma(qx, cx,
                      __builtin_elementwise_fma(qy, cy, qz * cz));
            v2f d2  = __builtin_elementwise_fma(m2, dot, qw + cw);
            tt[2*u]   = ((int)__float_as_uint(d2.x)) >> 20;
            tt[2*u+1] = ((int)__float_as_uint(d2.y)) >> 20;
            dd[2*u] = d2.x; dd[2*u+1] = d2.y;
        }
        #pragma unroll
        for (int u = 0; u < 16; ++u) {
            if (tt[u] < TL) {
                uint32_t pos = atomicAdd(&dirCnt[lane], 1u);
                idx_ws[grow * KK + (int)pos] = batch * NN + (j + u);
            } else if (tt[u] <= TH) {
                uint32_t db = __float_as_uint(fmaxf(dd[u], 0.0f)); // exact key
                uint32_t pos = atomicAdd(&bufCnt[lane], 1u);
                if (pos < 64u) buf[(int)pos * 64 + lane] =
                    ((unsigned long long)db << 32) | (uint32_t)(j + u);
            }
        }
    }
    __syncthreads();

    // ---- final: pick (36 - cumLo) smallest exact keys from boundary bin ----
    if (threadIdx.x < 64) {
        const int t = threadIdx.x;
        const int q2 = qbase + t;
        const int grow2 = batch * NN + q2;
        const int cl = cumLoA[t];
        const int r = KK - cl;
        const int M = min((int)bufCnt[t], 64);
        const int outp = grow2 * KK + cl;
        for (int i = 0; i < r; ++i) {
            unsigned long long best = ~0ULL; int bi = -1;
            for (int u = 0; u < M; ++u) {
                unsigned long long v = buf[u * 64 + t];
                if (v < best) { best = v; bi = u; }
            }
            int jj;
            if (bi >= 0) { buf[bi * 64 + t] = ~0ULL; jj = (int)(best & 0xFFFFFFFFu); }
            else jj = q2;                            // pathological fallback
            if (jj < 0 || jj >= NN) jj = q2;
            idx_ws[outp + i] = batch * NN + jj;
        }
    }
}

// ---------------------------------------------------------------------------
// Kernel 3: attention. One wave per point. Indices preloaded as 9 x int4
// (register-resident) and masked to [0,NPTS) (no-op for valid data; keeps
// rocprof isolated-replay with poisoned idxw from wild gathers).
// G staged in LDS stride-65 (conflict-free); 36 parallel logits; one
// butterfly max + sum; weighted-V gather; 64x64 projection.
// grid = NPTS/4 blocks of 256. No __syncthreads (waves independent).
// ---------------------------------------------------------------------------
#define IDX(k) ((((k) & 3) == 0 ? I[(k) >> 2].x : ((k) & 3) == 1 ? I[(k) >> 2].y : \
                 ((k) & 3) == 2 ? I[(k) >> 2].z : I[(k) >> 2].w) & (NPTS - 1))

__global__ __launch_bounds__(256) void k_att(
    const float* __restrict__ feat, const float* __restrict__ vfeat,
    const int* __restrict__ idxw, const float* __restrict__ Wsuf,
    const float* __restrict__ bsuf, float* __restrict__ out)
{
    __shared__ float G[4][KK][65];   // 37,440 B
    __shared__ float F[4][64];
    __shared__ float Wb[4][KK];
    __shared__ float accb[4][64];
    const int lane = laneid();
    const int wv = waveid_uniform();
    const int p = blockIdx.x * 4 + wv;

    // preload all 36 neighbor indices (KK*4 = 144 B, 16B-aligned for every p)
    const int4* __restrict__ myidx4 = (const int4*)(idxw + p * KK);
    int4 I[9];
    #pragma unroll
    for (int t = 0; t < 9; ++t) I[t] = myidx4[t];

    const float f = feat[p * CC + lane];
    F[wv][lane] = f;

    #pragma unroll
    for (int k = 0; k < KK; ++k) {
        int j = IDX(k);
        G[wv][k][lane] = feat[j * CC + lane];      // coalesced row gather
    }

    // logits: lane k (<36) sums over channels; G stride 65 = bank-conflict-free
    float logit = -1e30f;
    if (lane < KK) {
        float a = 0.0f;
        #pragma unroll 8
        for (int c = 0; c < CC; ++c)
            a = fmaf(F[wv][c], G[wv][lane][c], a);
        logit = a;
    }
    // softmax across the 36 logit lanes (others contribute -inf / 0)
    float m = logit;
    #pragma unroll
    for (int off = 32; off > 0; off >>= 1)
        m = fmaxf(m, __shfl_xor(m, off, 64));
    float e = (lane < KK) ? __expf(logit - m) : 0.0f;
    float s = e;
    #pragma unroll
    for (int off = 32; off > 0; off >>= 1)
        s += __shfl_xor(s, off, 64);
    if (lane < KK) Wb[wv][lane] = e / s;

    // weighted V gather: lane = channel
    float acc = 0.0f;
    #pragma unroll
    for (int k = 0; k < KK; ++k) {
        int j = IDX(k);
        acc = fmaf(Wb[wv][k], vfeat[j * OUTD + lane], acc);
    }
    accb[wv][lane] = acc;

    float o = bsuf[lane];
    #pragma unroll 8
    for (int c = 0; c < OUTD; ++c)
        o = fmaf(accb[wv][c], Wsuf[c * OUTD + lane], o);
    out[p * OUTD + lane] = o;

    if (p == 0 && lane == 0) out[NPTS * OUTD] = (float)NN;  // output 1: scalar N
}

// ---------------------------------------------------------------------------
extern "C" void kernel_launch(void* const* d_in, const int* in_sizes, int n_in,
                              void* d_out, int out_size, void* d_ws, size_t ws_size,
                              hipStream_t stream)
{
    const float* feat = (const float*)d_in[0];
    const float* xyz  = (const float*)d_in[1];
    const float* Wv   = (const float*)d_in[2];
    const float* bv   = (const float*)d_in[3];
    const float* Wsuf = (const float*)d_in[4];
    const float* bsuf = (const float*)d_in[5];
    float* out = (float*)d_out;

    char* ws = (char*)d_ws;
    float4* xyzw = (float4*)ws;                               // 512 KB
    float*  vfeat = (float*)(ws + (512 << 10));               // 8 MB
    int*    idxw  = (int*)(ws + (512 << 10) + (8 << 20));     // 4.5 MB

    k_vfeat<<<NPTS / 32, 256, 0, stream>>>(feat, xyz, Wv, bv, vfeat, xyzw);
    k_knn  <<<NPTS / 64, 1024, 0, stream>>>(xyzw, idxw);
    k_att  <<<NPTS / 4, 256, 0, stream>>>(feat, vfeat, idxw, Wsuf, bsuf, out);
}

// Round 11
// 295.904 us; speedup vs baseline: 1.1483x; 1.1483x over previous
//
#include <hip/hip_runtime.h>
#include <stdint.h>
#include <limits.h>

// Problem constants (reference: B=4, N=8192, C=64, OUT=64, KNN=36)
#define BB 4
#define NN 8192
#define CC 64
#define OUTD 64
#define KK 36
#define NPTS (BB * NN)          // 32768
#define NBIN 129                // bins 0..128 (0 and 128 are clamp catch-alls)
// t = signed(float_bits(d2)) >> 20 (arith); bin = med3_i32(t,960,1088) - 960.
// Negative d2 (fp rounding) -> t very negative -> bin 0. One integer t per bin.

typedef float v2f __attribute__((ext_vector_type(2)));

static __device__ __forceinline__ int laneid() { return threadIdx.x & 63; }
static __device__ __forceinline__ int waveid_uniform() {
    return __builtin_amdgcn_readfirstlane((int)(threadIdx.x >> 6));
}

// ---------------------------------------------------------------------------
// Kernel 1: v_feat = relu([feature, xyz] @ W_v + b_v)  and pack xyzw=(x,y,z,|p|^2)
// One wave handles 8 points (shares each Wv row load across 8 accumulators).
// Block = 256 = 4 waves = 32 points. grid = NPTS/32 = 1024 blocks.
// ---------------------------------------------------------------------------
__global__ __launch_bounds__(256) void k_vfeat(
    const float* __restrict__ feat, const float* __restrict__ xyz,
    const float* __restrict__ Wv, const float* __restrict__ bv,
    float* __restrict__ vfeat, float4* __restrict__ xyzw)
{
    __shared__ float fb[4][8][64];
    __shared__ float xb[4][8][3];
    const int lane = laneid();
    const int wv = waveid_uniform();
    const int pbase = blockIdx.x * 32 + wv * 8;

    #pragma unroll
    for (int pp = 0; pp < 8; ++pp)
        fb[wv][pp][lane] = feat[(pbase + pp) * CC + lane];
    if (lane < 24)
        xb[wv][lane / 3][lane % 3] = xyz[pbase * 3 + lane];
    // same-wave LDS write->read: in-order per wave, compiler inserts lgkmcnt

    const float b0 = bv[lane];
    float acc[8];
    #pragma unroll
    for (int pp = 0; pp < 8; ++pp) acc[pp] = b0;

    #pragma unroll 4
    for (int c = 0; c < CC; ++c) {
        float w = Wv[c * OUTD + lane];
        #pragma unroll
        for (int pp = 0; pp < 8; ++pp)
            acc[pp] = fmaf(fb[wv][pp][c], w, acc[pp]);
    }
    const float wx = Wv[64 * OUTD + lane];
    const float wy = Wv[65 * OUTD + lane];
    const float wz = Wv[66 * OUTD + lane];
    #pragma unroll
    for (int pp = 0; pp < 8; ++pp) {
        float a = acc[pp];
        a = fmaf(xb[wv][pp][0], wx, a);
        a = fmaf(xb[wv][pp][1], wy, a);
        a = fmaf(xb[wv][pp][2], wz, a);
        vfeat[(pbase + pp) * OUTD + lane] = fmaxf(a, 0.0f);
    }
    if (lane < 8) {
        float x = xb[wv][lane][0], y = xb[wv][lane][1], z = xb[wv][lane][2];
        float sq = (x * x + y * y) + z * z;
        xyzw[pbase + lane] = make_float4(x, y, z, sq);
    }
}

// ---------------------------------------------------------------------------
// Kernel 2: 36-NN via per-query float-bit histogram selection. (R7 revert —
// best measured: 185 us, VALUBusy 46%, occ 73%, SGPR 48. Keep SGPR <= 64:
// larger load windows blow the ~800/SIMD SGPR file and halve occupancy.)
// 512 blocks x 1024 thr, 64 queries/block = lane-per-query, 2 blocks/CU;
// packed candidate pairs (v_pk_fma_f32), AoS float4 via wave-uniform s_load.
// Histogram hist[bin][lane]: bank = lane%32, conflict-free 32-bit counts.
// Tie-break matches lax.top_k: (distance-bits, then smaller index).
// ---------------------------------------------------------------------------
__global__ __launch_bounds__(1024) void k_knn(
    const float4* __restrict__ xyzw, int* __restrict__ idx_ws)
{
    __shared__ __align__(16) uint32_t hist[NBIN * 64];  // 33 KB; reused as buf in pass 2
    __shared__ int binB[64];
    __shared__ int cumLoA[64];
    __shared__ uint32_t bufCnt[64];
    __shared__ uint32_t dirCnt[64];

    const int lane = laneid();
    const int wv = waveid_uniform();               // 0..15
    const int batch = blockIdx.x >> 7;             // 128 blocks per batch
    const int qbase = (blockIdx.x & 127) << 6;
    const int q = qbase + lane;                    // local query id 0..8191
    const float4* __restrict__ xw = xyzw + batch * NN;

    const float4 Q = xw[q];
    const v2f qx = { Q.x, Q.x };
    const v2f qy = { Q.y, Q.y };
    const v2f qz = { Q.z, Q.z };
    const v2f qw = { Q.w, Q.w };
    const v2f m2 = { -2.0f, -2.0f };

    const int j0 = wv * 512;
    const int laneAdj = lane - 960 * 64;           // fold bin rebase into addressing

    for (int i = threadIdx.x; i < NBIN * 64; i += 1024) hist[i] = 0u;
    if (threadIdx.x < 64) { bufCnt[threadIdx.x] = 0u; dirCnt[threadIdx.x] = 0u; }
    __syncthreads();

    // ---- pass 1: histogram of distance bits (2 candidates / iteration) ----
    #pragma unroll 4
    for (int j = j0; j < j0 + 512; j += 2) {
        float4 C0 = xw[j];                         // merged s_load_dwordx8
        float4 C1 = xw[j + 1];
        v2f cx = { C0.x, C1.x }, cy = { C0.y, C1.y };
        v2f cz = { C0.z, C1.z }, cw = { C0.w, C1.w };
        v2f dot = __builtin_elementwise_fma(qx, cx,
                  __builtin_elementwise_fma(qy, cy, qz * cz));
        v2f d2  = __builtin_elementwise_fma(m2, dot, qw + cw);
        int t0 = ((int)__float_as_uint(d2.x)) >> 20;   // arith shift: neg d -> very neg
        int t1 = ((int)__float_as_uint(d2.y)) >> 20;
        int m30 = min(max(t0, 960), 1088);             // v_med3_i32
        int m31 = min(max(t1, 960), 1088);
        atomicAdd(&hist[m30 * 64 + laneAdj], 1u);      // == hist[bin*64 + lane]
        atomicAdd(&hist[m31 * 64 + laneAdj], 1u);
    }
    __syncthreads();

    // ---- find crossing bin (threads 0..63, one query each) ----
    if (threadIdx.x < 64) {
        int cum = 0, Bq = 128, cl = 0;
        for (int b2 = 0; b2 < NBIN; ++b2) {
            int c = (int)hist[b2 * 64 + threadIdx.x];
            if (cum + c >= KK) { Bq = b2; cl = cum; break; }
            cum += c;
        }
        binB[threadIdx.x] = Bq;
        cumLoA[threadIdx.x] = cl;
    }
    __syncthreads();

    // ---- per-lane integer thresholds for pass 2 ----
    // direct (bin < Bq)    <=>  t <  TL
    // boundary (bin == Bq) <=>  !direct && t <= TH
    const int Bq = binB[lane];
    const int TL = (Bq > 0)    ? (960 + Bq) : INT_MIN;
    const int TH = (Bq == 128) ? INT_MAX    : (960 + Bq);
    const int grow = batch * NN + q;

    // buf[pos][lane] (transposed): 64 pos x 64 lanes x 8B = 32 KB (inside hist)
    unsigned long long* buf = (unsigned long long*)hist;

    // ---- pass 2: direct-emit strict members; buffer boundary-bin members ----
    #pragma unroll 4
    for (int j = j0; j < j0 + 512; j += 2) {
        float4 C0 = xw[j];
        float4 C1 = xw[j + 1];
        v2f cx = { C0.x, C1.x }, cy = { C0.y, C1.y };
        v2f cz = { C0.z, C1.z }, cw = { C0.w, C1.w };
        v2f dot = __builtin_elementwise_fma(qx, cx,
                  __builtin_elementwise_fma(qy, cy, qz * cz));
        v2f d2  = __builtin_elementwise_fma(m2, dot, qw + cw);
        int t0 = ((int)__float_as_uint(d2.x)) >> 20;
        int t1 = ((int)__float_as_uint(d2.y)) >> 20;
        if (t0 < TL) {
            uint32_t pos = atomicAdd(&dirCnt[lane], 1u);
            idx_ws[grow * KK + (int)pos] = batch * NN + j;
        } else if (t0 <= TH) {
            uint32_t db = __float_as_uint(fmaxf(d2.x, 0.0f));   // exact monotone key
            uint32_t pos = atomicAdd(&bufCnt[lane], 1u);
            if (pos < 64u) buf[(int)pos * 64 + lane] =
                ((unsigned long long)db << 32) | (uint32_t)j;
        }
        if (t1 < TL) {
            uint32_t pos = atomicAdd(&dirCnt[lane], 1u);
            idx_ws[grow * KK + (int)pos] = batch * NN + (j + 1);
        } else if (t1 <= TH) {
            uint32_t db = __float_as_uint(fmaxf(d2.y, 0.0f));
            uint32_t pos = atomicAdd(&bufCnt[lane], 1u);
            if (pos < 64u) buf[(int)pos * 64 + lane] =
                ((unsigned long long)db << 32) | (uint32_t)(j + 1);
        }
    }
    __syncthreads();

    // ---- final: pick (36 - cumLo) smallest exact keys from boundary bin ----
    if (threadIdx.x < 64) {
        const int t = threadIdx.x;
        const int q2 = qbase + t;
        const int grow2 = batch * NN + q2;
        const int cl = cumLoA[t];
        const int r = KK - cl;
        const int M = min((int)bufCnt[t], 64);
        const int outp = grow2 * KK + cl;
        for (int i = 0; i < r; ++i) {
            unsigned long long best = ~0ULL; int bi = -1;
            for (int u = 0; u < M; ++u) {
                unsigned long long v = buf[u * 64 + t];
                if (v < best) { best = v; bi = u; }
            }
            int jj;
            if (bi >= 0) { buf[bi * 64 + t] = ~0ULL; jj = (int)(best & 0xFFFFFFFFu); }
            else jj = q2;                            // pathological fallback
            if (jj < 0 || jj >= NN) jj = q2;
            idx_ws[outp + i] = batch * NN + jj;
        }
    }
}

// ---------------------------------------------------------------------------
// Kernel 3: attention. One wave per point. LDS halved vs prior round:
// G staged in TWO half-channel rounds (G[4][36][33], ~21.6 KB total block LDS
// vs 40 KB) -> 7 blocks/CU (~87% occupancy) instead of 4 (50%).
// Each gather wave-load covers two rows' same 32-col half (lane split).
// 36 parallel logits; butterfly max+sum; weighted-V gather; 64x64 projection.
// grid = NPTS/4 blocks of 256. No __syncthreads (waves independent).
// ---------------------------------------------------------------------------
#define IDX(k) ((((k) & 3) == 0 ? I[(k) >> 2].x : ((k) & 3) == 1 ? I[(k) >> 2].y : \
                 ((k) & 3) == 2 ? I[(k) >> 2].z : I[(k) >> 2].w) & (NPTS - 1))

__global__ __launch_bounds__(256) void k_att(
    const float* __restrict__ feat, const float* __restrict__ vfeat,
    const int* __restrict__ idxw, const float* __restrict__ Wsuf,
    const float* __restrict__ bsuf, float* __restrict__ out)
{
    __shared__ float G[4][KK][33];   // 19,008 B  (stride 33 == 1 mod 32: <=2-way)
    __shared__ float F[4][64];
    __shared__ float Wb[4][KK];
    __shared__ float accb[4][64];
    const int lane = laneid();
    const int wv = waveid_uniform();
    const int p = blockIdx.x * 4 + wv;

    // preload all 36 neighbor indices (KK*4 = 144 B, 16B-aligned for every p)
    const int4* __restrict__ myidx4 = (const int4*)(idxw + p * KK);
    int4 I[9];
    #pragma unroll
    for (int t = 0; t < 9; ++t) I[t] = myidx4[t];

    const float f = feat[p * CC + lane];
    F[wv][lane] = f;

    const int half = lane >> 5;       // 0: rows 2kk, 1: rows 2kk+1
    const int cpart = lane & 31;      // column within the 32-wide half

    float logit = -1e30f;
    float a = 0.0f;
    #pragma unroll
    for (int h = 0; h < 2; ++h) {
        // stage half h: 18 wave-loads, each covering two rows' 32-col halves
        #pragma unroll
        for (int kk = 0; kk < 18; ++kk) {
            int jrow = half ? IDX(2 * kk + 1) : IDX(2 * kk);
            G[wv][2 * kk + half][cpart] = feat[jrow * CC + h * 32 + cpart];
        }
        // partial logits over this channel half (lane = k < 36)
        if (lane < KK) {
            #pragma unroll 8
            for (int c = 0; c < 32; ++c)
                a = fmaf(F[wv][h * 32 + c], G[wv][lane][c], a);
        }
    }
    if (lane < KK) logit = a;

    // softmax across the 36 logit lanes (others contribute -inf / 0)
    float m = logit;
    #pragma unroll
    for (int off = 32; off > 0; off >>= 1)
        m = fmaxf(m, __shfl_xor(m, off, 64));
    float e = (lane < KK) ? __expf(logit - m) : 0.0f;
    float s = e;
    #pragma unroll
    for (int off = 32; off > 0; off >>= 1)
        s += __shfl_xor(s, off, 64);
    if (lane < KK) Wb[wv][lane] = e / s;

    // weighted V gather: lane = channel
    float acc = 0.0f;
    #pragma unroll
    for (int k = 0; k < KK; ++k) {
        int j = IDX(k);
        acc = fmaf(Wb[wv][k], vfeat[j * OUTD + lane], acc);
    }
    accb[wv][lane] = acc;

    float o = bsuf[lane];
    #pragma unroll 8
    for (int c = 0; c < OUTD; ++c)
        o = fmaf(accb[wv][c], Wsuf[c * OUTD + lane], o);
    out[p * OUTD + lane] = o;

    if (p == 0 && lane == 0) out[NPTS * OUTD] = (float)NN;  // output 1: scalar N
}

// ---------------------------------------------------------------------------
extern "C" void kernel_launch(void* const* d_in, const int* in_sizes, int n_in,
                              void* d_out, int out_size, void* d_ws, size_t ws_size,
                              hipStream_t stream)
{
    const float* feat = (const float*)d_in[0];
    const float* xyz  = (const float*)d_in[1];
    const float* Wv   = (const float*)d_in[2];
    const float* bv   = (const float*)d_in[3];
    const float* Wsuf = (const float*)d_in[4];
    const float* bsuf = (const float*)d_in[5];
    float* out = (float*)d_out;

    char* ws = (char*)d_ws;
    float4* xyzw = (float4*)ws;                               // 512 KB
    float*  vfeat = (float*)(ws + (512 << 10));               // 8 MB
    int*    idxw  = (int*)(ws + (512 << 10) + (8 << 20));     // 4.5 MB

    k_vfeat<<<NPTS / 32, 256, 0, stream>>>(feat, xyz, Wv, bv, vfeat, xyzw);
    k_knn  <<<NPTS / 64, 1024, 0, stream>>>(xyzw, idxw);
    k_att  <<<NPTS / 4, 256, 0, stream>>>(feat, vfeat, idxw, Wsuf, bsuf, out);
}